// Round 3
// baseline (691.044 us; speedup 1.0000x reference)
//
#include <hip/hip_runtime.h>
#include <hip/hip_bf16.h>
#include <hip/hip_fp16.h>

// Problem dims
#define A_DIM 4608   // C*9 patch-feature rows
#define L_DIM 4096   // (H/3)*(W/3) spatial columns
#define CH    512
#define H_DIM 192
#define W_DIM 192

// GEMM tile (R9: 128x192, 2x3-frag 64x96 wave tile; LDS 80 KB, 2 blocks/CU)
#define BM 128
#define BN 192
#define BK 32        // 4 kchunks of 8 halves per stage
#define NS (L_DIM / BK)

#define CPB 32       // prep: channels per block

typedef _Float16 half8 __attribute__((ext_vector_type(8)));
typedef float   floatx4 __attribute__((ext_vector_type(4)));
typedef float   floatx16 __attribute__((ext_vector_type(16)));

// ---------------------------------------------------------------------------
// Pass 1: unfold(x) -> k-chunk-major f16 hi/lo split + global sum-of-squares
// accumulation (ss arrays pre-zeroed; block atomicAdds its partials).
// Global layout: U[(l>>3)*A_DIM + a][8] (chunk-major; GEMM staging contiguous
// and conflict-free — verified: GEMM SQ_LDS_BANK_CONFLICT = 0).
// ---------------------------------------------------------------------------
__global__ __launch_bounds__(256) void prep_kernel(
    const float* __restrict__ x0, const float* __restrict__ x1,
    _Float16* __restrict__ Uhi0, _Float16* __restrict__ Ulo0,
    _Float16* __restrict__ Uhi1, _Float16* __restrict__ Ulo1,
    float* __restrict__ ss0, float* __restrict__ ss1) {
  const int which = blockIdx.z;
  const float* __restrict__ x = which ? x1 : x0;
  _Float16* __restrict__ Uhi = which ? Uhi1 : Uhi0;
  _Float16* __restrict__ Ulo = which ? Ulo1 : Ulo0;
  float* __restrict__ ssg = which ? ss1 : ss0;

  const int ph = blockIdx.y;            // 0..63
  const int c0 = blockIdx.x * CPB;      // channel group base
  const int abase = blockIdx.x * (CPB * 9);

  __shared__ _Float16 sHi[CPB * 9 * 8 * 8];  // 288 rows x 8 chunks x 8 halves
  __shared__ _Float16 sLo[CPB * 9 * 8 * 8];
  __shared__ float ssb[CPB * 9];

  const int t = threadIdx.x;
  for (int a = t; a < CPB * 9; a += 256) ssb[a] = 0.f;
  __syncthreads();

  // ---- phase 1: read input, assemble 16B chunks in regs, stage in LDS
  const int c_l = t >> 3;               // 0..31
  const int s = t & 7;                  // chunk index this thread owns
  const float* __restrict__ rowbase =
      x + ((size_t)(c0 + c_l) * H_DIM + 3 * ph) * W_DIM + s * 24;
  float ssp[9] = {0.f, 0.f, 0.f, 0.f, 0.f, 0.f, 0.f, 0.f, 0.f};

#pragma unroll
  for (int kh = 0; kh < 3; ++kh) {
    const float* __restrict__ rp = rowbase + kh * W_DIM;
    floatx4 v4[6];
#pragma unroll
    for (int i = 0; i < 6; ++i) v4[i] = *(const floatx4*)(rp + i * 4);
    half8 hv[3], lv[3];
#pragma unroll
    for (int i = 0; i < 6; ++i)
#pragma unroll
      for (int j = 0; j < 4; ++j) {
        const int m = i * 4 + j;        // 0..23
        const int kw = m % 3, e = m / 3;
        const float v = v4[i][j];
        ssp[kh * 3 + kw] += v * v;
        const _Float16 h = (_Float16)v;
        hv[kw][e] = h;
        lv[kw][e] = (_Float16)(v - (float)h);
      }
#pragma unroll
    for (int kw = 0; kw < 3; ++kw) {
      const int a_l = c_l * 9 + kh * 3 + kw;
      const int addr = (a_l * 8 + (s ^ (a_l & 7))) * 8;  // XOR-swizzled chunk
      *(half8*)&sHi[addr] = hv[kw];
      *(half8*)&sLo[addr] = lv[kw];
    }
  }
#pragma unroll
  for (int q = 0; q < 9; ++q) atomicAdd(&ssb[c_l * 9 + q], ssp[q]);
  __syncthreads();

  // ---- phase 2: coalesced global writes (consecutive t = consecutive a)
#pragma unroll
  for (int i = 0; i < 9; ++i) {
    const int idx = i * 256 + t;        // 0..2303
    const int c8 = idx / 288;
    const int a_l = idx - c8 * 288;
    const int addr = (a_l * 8 + (c8 ^ (a_l & 7))) * 8;
    const size_t g = ((size_t)(ph * 8 + c8) * A_DIM + abase + a_l) * 8;
    *(half8*)&Uhi[g] = *(const half8*)&sHi[addr];
    *(half8*)&Ulo[g] = *(const half8*)&sLo[addr];
  }
  // ---- global norm accumulation (cross-block over ph)
  for (int a = t; a < CPB * 9; a += 256) atomicAdd(&ssg[abase + a], ssb[a]);
}

// ---------------------------------------------------------------------------
// Pass 2: D[i,j] = sty_i . img_j, 3-term f16 split, 32x32x16 MFMA, 128x192
// tile, double-buffered LDS with the proven loop order:
//   ISSUE(ks+1) -> s_waitcnt vmcnt(10) -> s_barrier -> compute -> s_barrier.
// (Never cross the barrier with an empty VMEM queue.)
//
// R10: at 53% MfmaUtil the kernel runs LDS-port and MFMA-pipe SERIALIZED
// (per macro-step: 2570 LDS cyc + 2304 MFMA cyc ~= 5389 measured). Cause:
// in-order wave issue of [20 reads][36 MFMAs] bursts + port-coupled phase
// locking of the two resident blocks. Fix: 6 clusters of 6 MFMAs per K-step,
// each cluster prefetches the next cluster's fragments (register ping-pong)
// before its MFMAs; sched_barrier(0) pins cluster boundaries; setprio(1)
// around MFMA clusters (T5). Accumulate order per acc element unchanged ->
// bit-identical output.
//
// Block swizzle (1-D grid, 864 = 3*288 blocks): id -> (bx,by) such that XCD
// (heuristic id%8) pins one B col-tile (3 MB, fits 4 MB XCD-L2) across all
// 36 by-steps.
// ---------------------------------------------------------------------------
#define GLDS(g, l)                                                          \
  __builtin_amdgcn_global_load_lds(                                        \
      (const __attribute__((address_space(1))) void*)(g),                   \
      (__attribute__((address_space(3))) void*)(l), 16, 0, 0)

#define MM6(AH, AL, BH, BL, CF)                                             \
  do {                                                                      \
    acc[0][CF] = __builtin_amdgcn_mfma_f32_32x32x16_f16(AH[0], BH,          \
                                                        acc[0][CF], 0, 0, 0); \
    acc[1][CF] = __builtin_amdgcn_mfma_f32_32x32x16_f16(AH[1], BH,          \
                                                        acc[1][CF], 0, 0, 0); \
    acc[0][CF] = __builtin_amdgcn_mfma_f32_32x32x16_f16(AH[0], BL,          \
                                                        acc[0][CF], 0, 0, 0); \
    acc[1][CF] = __builtin_amdgcn_mfma_f32_32x32x16_f16(AH[1], BL,          \
                                                        acc[1][CF], 0, 0, 0); \
    acc[0][CF] = __builtin_amdgcn_mfma_f32_32x32x16_f16(AL[0], BH,          \
                                                        acc[0][CF], 0, 0, 0); \
    acc[1][CF] = __builtin_amdgcn_mfma_f32_32x32x16_f16(AL[1], BH,          \
                                                        acc[1][CF], 0, 0, 0); \
  } while (0)

#define SCHED __builtin_amdgcn_sched_barrier(0)
#define PRIO1 __builtin_amdgcn_s_setprio(1)
#define PRIO0 __builtin_amdgcn_s_setprio(0)

__global__ __launch_bounds__(256, 2) void gemm_max_kernel(
    const _Float16* __restrict__ Shi, const _Float16* __restrict__ Slo,
    const _Float16* __restrict__ Ihi, const _Float16* __restrict__ Ilo,
    const float* __restrict__ img_ss,
    unsigned long long* __restrict__ packed) {
  // Per-buffer layout (halves): Ah[0,4096) Al[4096,8192) Bh[8192,14336)
  // Bl[14336,20480). 4 kchunks x {128 A rows | 192 B rows} x 8 halves. 80 KB.
  __shared__ _Float16 sm[2][20480];

  const int t = threadIdx.x;
  const int lane = t & 63, wv = t >> 6;
  const int wvr = wv >> 1, wvc = wv & 1;       // 2x2 waves, wave tile 64x96
  // swizzled block mapping: 3 groups of 8 bx columns; within a group,
  // consecutive linear ids step `by` with bx_lo (=XCD slot) fixed.
  const int id = blockIdx.x;
  const int g = id / 288, r = id - g * 288;
  const int by = r >> 3, bx = g * 8 + (r & 7);
  const int row0 = by * BM;                    // sty rows (i)
  const int col0 = bx * BN;                    // img rows (j)
  const int l31 = lane & 31, hs = lane >> 5;

  floatx16 acc[2][3];
#pragma unroll
  for (int rf = 0; rf < 2; ++rf)
#pragma unroll
    for (int cf = 0; cf < 3; ++cf) acc[rf][cf] = (floatx16)0.f;

  // Staging. A: thread t covers (plane = t>>7, row = t&127); two GLDS per
  // matrix (planes +0, +2). B: 3 chunks c = i*256+t, (kc = c/192, row = c%192)
  // precomputed. LDS dest = linear 16B/thread (wave-uniform base + lane*16).
  const size_t CH8 = (size_t)A_DIM * 8;        // one kchunk plane, in halves
  const size_t aOff = (size_t)(t >> 7) * CH8 + (size_t)(row0 + (t & 127)) * 8;
  size_t bOff[3];
#pragma unroll
  for (int i = 0; i < 3; ++i) {
    const int c = i * 256 + t;                 // 0..767
    const int kc = c / 192, rw = c - kc * 192;
    bOff[i] = (size_t)kc * CH8 + (size_t)(col0 + rw) * 8;
  }
  const int dl = t * 8;  // halves == t*16 bytes

#define ISSUE(b, koff)                                            \
  do {                                                            \
    GLDS(Shi + (koff) + aOff,           &sm[b][dl]);              \
    GLDS(Shi + (koff) + aOff + 2 * CH8, &sm[b][dl + 2048]);       \
    GLDS(Slo + (koff) + aOff,           &sm[b][4096 + dl]);       \
    GLDS(Slo + (koff) + aOff + 2 * CH8, &sm[b][4096 + dl + 2048]);\
    GLDS(Ihi + (koff) + bOff[0], &sm[b][8192 + dl]);              \
    GLDS(Ihi + (koff) + bOff[1], &sm[b][8192 + dl + 2048]);       \
    GLDS(Ihi + (koff) + bOff[2], &sm[b][8192 + dl + 4096]);       \
    GLDS(Ilo + (koff) + bOff[0], &sm[b][14336 + dl]);             \
    GLDS(Ilo + (koff) + bOff[1], &sm[b][14336 + dl + 2048]);      \
    GLDS(Ilo + (koff) + bOff[2], &sm[b][14336 + dl + 4096]);      \
  } while (0)

  ISSUE(0, 0);  // prologue prefetch of stage 0

  for (int ks = 0; ks < NS; ++ks) {
    const int cur = ks & 1;
    if (ks + 1 < NS) {
      ISSUE(1 - cur, (size_t)(ks + 1) * 4 * CH8);
      asm volatile("s_waitcnt vmcnt(10)" ::: "memory");  // stage ks complete
    } else {
      asm volatile("s_waitcnt vmcnt(0)" ::: "memory");
    }
    asm volatile("s_barrier" ::: "memory");  // all waves' stage-ks data in LDS

    const _Float16* __restrict__ S = &sm[cur][0];
    // Per-lane-half kchunks: kk0 -> kc=hs, kk1 -> kc=2+hs.
    const int aA = ((hs)*128 + wvr * 64 + l31) * 8;       // kk0 A base (rf0)
    const int aB = ((2 + hs) * 128 + wvr * 64 + l31) * 8; // kk1 A base (rf0)
    const int bA = ((hs)*192 + wvc * 96 + l31) * 8;       // kk0 B base (cf0)
    const int bB = ((2 + hs) * 192 + wvc * 96 + l31) * 8; // kk1 B base (cf0)

    half8 ah0[2], al0[2], ah1[2], al1[2], bhX, blX, bhY, blY;
    // lead-in: kk0 A frags + (kk0, cf0) B frags                 [6 reads]
    ah0[0] = *(const half8*)&S[aA];
    ah0[1] = *(const half8*)&S[aA + 256];
    al0[0] = *(const half8*)&S[4096 + aA];
    al0[1] = *(const half8*)&S[4096 + aA + 256];
    bhX = *(const half8*)&S[8192 + bA];
    blX = *(const half8*)&S[14336 + bA];
    SCHED;
    // prefetch (kk0, cf1)                                       [2 reads]
    bhY = *(const half8*)&S[8192 + bA + 256];
    blY = *(const half8*)&S[14336 + bA + 256];
    SCHED;
    PRIO1; MM6(ah0, al0, bhX, blX, 0); PRIO0;   // cluster 0: kk0 cf0
    SCHED;
    // prefetch (kk0, cf2)                                       [2 reads]
    bhX = *(const half8*)&S[8192 + bA + 512];
    blX = *(const half8*)&S[14336 + bA + 512];
    SCHED;
    PRIO1; MM6(ah0, al0, bhY, blY, 1); PRIO0;   // cluster 1: kk0 cf1
    SCHED;
    // prefetch kk1 A frags + (kk1, cf0)                         [6 reads]
    ah1[0] = *(const half8*)&S[aB];
    ah1[1] = *(const half8*)&S[aB + 256];
    al1[0] = *(const half8*)&S[4096 + aB];
    al1[1] = *(const half8*)&S[4096 + aB + 256];
    bhY = *(const half8*)&S[8192 + bB];
    blY = *(const half8*)&S[14336 + bB];
    SCHED;
    PRIO1; MM6(ah0, al0, bhX, blX, 2); PRIO0;   // cluster 2: kk0 cf2
    SCHED;
    // prefetch (kk1, cf1)                                       [2 reads]
    bhX = *(const half8*)&S[8192 + bB + 256];
    blX = *(const half8*)&S[14336 + bB + 256];
    SCHED;
    PRIO1; MM6(ah1, al1, bhY, blY, 0); PRIO0;   // cluster 3: kk1 cf0
    SCHED;
    // prefetch (kk1, cf2)                                       [2 reads]
    bhY = *(const half8*)&S[8192 + bB + 512];
    blY = *(const half8*)&S[14336 + bB + 512];
    SCHED;
    PRIO1; MM6(ah1, al1, bhX, blX, 1); PRIO0;   // cluster 4: kk1 cf1
    SCHED;
    PRIO1; MM6(ah1, al1, bhY, blY, 2); PRIO0;   // cluster 5: kk1 cf2
    asm volatile("s_barrier" ::: "memory");  // reads done before overwrite
  }

  // Epilogue: v[i,j] = rsqrt(img_ss[i]) * D[i,j]; column max+argmax
  // (first-index wins). 32x32 C/D: col=lane&31, row=(reg&3)+8*(reg>>2)+4*hs.
  float nrv[2][16];
#pragma unroll
  for (int rf = 0; rf < 2; ++rf) {
    const int base_i = row0 + wvr * 64 + rf * 32 + 4 * hs;
#pragma unroll
    for (int g2 = 0; g2 < 4; ++g2) {
      const floatx4 s4 = *(const floatx4*)&img_ss[base_i + 8 * g2];
#pragma unroll
      for (int r2 = 0; r2 < 4; ++r2) nrv[rf][g2 * 4 + r2] = 1.0f / sqrtf(s4[r2]);
    }
  }
#pragma unroll
  for (int cf = 0; cf < 3; ++cf) {
    const int j = col0 + wvc * 96 + cf * 32 + l31;
    float best = -3.4e38f;
    int bi = 0x7FFFFFFF;
#pragma unroll
    for (int rf = 0; rf < 2; ++rf) {
      const int base_i = row0 + wvr * 64 + rf * 32 + 4 * hs;
#pragma unroll
      for (int g2 = 0; g2 < 4; ++g2)
#pragma unroll
        for (int r2 = 0; r2 < 4; ++r2) {
          const int i = base_i + 8 * g2 + r2;
          const float v = acc[rf][cf][g2 * 4 + r2] * nrv[rf][g2 * 4 + r2];
          if (v > best) { best = v; bi = i; }  // ascending i => first wins
        }
    }
    const float ov = __shfl_xor(best, 32, 64);
    const int oi = __shfl_xor(bi, 32, 64);
    if (ov > best || (ov == best && oi < bi)) { best = ov; bi = oi; }
    if (hs == 0) {
      const unsigned u = __float_as_uint(best);
      const unsigned key = (u & 0x80000000u) ? ~u : (u | 0x80000000u);
      const unsigned long long pk =
          ((unsigned long long)key << 32) | (unsigned)(~(unsigned)bi);
      atomicMax(&packed[j], pk);
    }
  }
}

// ---------------------------------------------------------------------------
// Pass 3: decode packed, apply rsqrt(sty_ss[j]); out[0..A)=nearest,
// out[A..2A)=max_sim.
// ---------------------------------------------------------------------------
__global__ __launch_bounds__(256) void finalize_kernel(
    const unsigned long long* __restrict__ packed,
    const float* __restrict__ sty_ss, float* __restrict__ out) {
  const int j = blockIdx.x * 256 + threadIdx.x;
  if (j >= A_DIM) return;
  const unsigned long long p = packed[j];
  const unsigned key = (unsigned)(p >> 32);
  const unsigned u = (key & 0x80000000u) ? (key ^ 0x80000000u) : ~key;
  const float v = __uint_as_float(u);
  const int idx = (int)(~(unsigned)(p & 0xFFFFFFFFu));
  out[j] = (float)idx;
  out[A_DIM + j] = v * (1.0f / sqrtf(sty_ss[j]));
}

extern "C" void kernel_launch(void* const* d_in, const int* in_sizes, int n_in,
                              void* d_out, int out_size, void* d_ws, size_t ws_size,
                              hipStream_t stream) {
  const float* model = (const float*)d_in[0];  // img side
  const float* style = (const float*)d_in[1];  // sty side
  float* out = (float*)d_out;
  char* ws = (char*)d_ws;

  const size_t usz = (size_t)A_DIM * L_DIM * 2;  // one f16 matrix: 37,748,736 B
  _Float16* img_hi = (_Float16*)(ws);
  _Float16* img_lo = (_Float16*)(ws + usz);
  _Float16* sty_hi = (_Float16*)(ws + 2 * usz);
  _Float16* sty_lo = (_Float16*)(ws + 3 * usz);
  float* img_ss = (float*)(ws + 4 * usz);        // zeroed accumulators
  float* sty_ss = img_ss + A_DIM;
  unsigned long long* packed = (unsigned long long*)(img_ss + 2 * A_DIM);

  // zero ss accumulators (2*A*4 B) + packed (A*8 B) in one contiguous memset
  hipMemsetAsync(img_ss, 0, (size_t)A_DIM * 16, stream);
  prep_kernel<<<dim3(CH / CPB, H_DIM / 3, 2), 256, 0, stream>>>(
      model, style, img_hi, img_lo, sty_hi, sty_lo, img_ss, sty_ss);
  gemm_max_kernel<<<dim3((A_DIM / BM) * (A_DIM / BN)), 256, 0, stream>>>(
      sty_hi, sty_lo, img_hi, img_lo, img_ss, packed);
  finalize_kernel<<<18, 256, 0, stream>>>(packed, sty_ss, out);
}